// Round 4
// baseline (62409.180 us; speedup 1.0000x reference)
//
#include <hip/hip_runtime.h>
#include <hip/hip_bf16.h>
#include <stdint.h>

// DeepAR decoder: L=3, B=512, H=1024, TAU=96, T=8, BETA=2
// Persistent-kernel version: all 289 GEMM phases in ONE kernel with a
// device-scope grid barrier between phases. grid=256 blocks x 512 thr,
// 99 KB LDS/block -> exactly 1 block/CU (co-residency guaranteed).
//
// ws layout (bytes):
//   Wih_b  bf16 [3][4096][1024]   @ 0          (25165824)
//   Whh_b  bf16 [3][4096][1024]   @ 25165824   (25165824)
//   h_b    bf16 [3][512][1024]    @ 50331648   (3145728)
//   gbuf   f32  [3][2M]           @ 53477376   (25165824)  (MFMA C-layout tiles)
//   bias   f32  [3][4096]         @ 78643200   (49152)
//   macc   f32  [512][96][16]     @ 78692352   (3145728)
//   bar    int  [1024]            @ 81838080   (4096)

typedef __attribute__((ext_vector_type(8))) short short8;
typedef __attribute__((ext_vector_type(8))) __bf16 bf16x8_t;
typedef __attribute__((ext_vector_type(4))) float f32x4;
typedef __attribute__((ext_vector_type(4))) unsigned short u16x4;

static __device__ __forceinline__ unsigned short f2bf(float f) {
  unsigned int u = __float_as_uint(f);
  u += 0x7FFFu + ((u >> 16) & 1u);  // RNE
  return (unsigned short)(u >> 16);
}
static __device__ __forceinline__ float sigm(float x) {
  return 1.0f / (1.0f + __expf(-x));
}
static __device__ __forceinline__ float tanh_f(float x) {
  float xc = fminf(fmaxf(x, -15.f), 15.f);
  float e = __expf(2.0f * xc);
  return 1.0f - 2.0f / (e + 1.0f);
}
static __device__ __forceinline__ void gload_lds16(const void* g, void* l) {
  __builtin_amdgcn_global_load_lds(
      (const __attribute__((address_space(1))) unsigned int*)g,
      (__attribute__((address_space(3))) unsigned int*)l, 16, 0, 0);
}
static __device__ __forceinline__ f32x4 mfma16(short8 a, short8 b, f32x4 c) {
  return __builtin_amdgcn_mfma_f32_16x16x32_bf16((bf16x8_t)a, (bf16x8_t)b, c, 0, 0, 0);
}

// Two-level grid barrier (8 groups of 32 blocks; counters on separate lines).
// Release fence before arrive, acquire fence after observe -> cross-XCD safe.
static __device__ __forceinline__ void grid_barrier(int* bar, int gen) {
  __threadfence();
  __syncthreads();
  if (threadIdx.x == 0) {
    const int g = blockIdx.x >> 5;
    int* gcnt = bar + 32 + g * 32;
    int* ggen = gcnt + 16;
    if (__hip_atomic_fetch_add(gcnt, 1, __ATOMIC_ACQ_REL,
                               __HIP_MEMORY_SCOPE_AGENT) == 31) {
      __hip_atomic_store(gcnt, 0, __ATOMIC_RELAXED, __HIP_MEMORY_SCOPE_AGENT);
      if (__hip_atomic_fetch_add(bar, 1, __ATOMIC_ACQ_REL,
                                 __HIP_MEMORY_SCOPE_AGENT) == 7) {
        __hip_atomic_store(bar, 0, __ATOMIC_RELAXED, __HIP_MEMORY_SCOPE_AGENT);
        __hip_atomic_store(bar + 16, gen + 1, __ATOMIC_RELEASE,
                           __HIP_MEMORY_SCOPE_AGENT);
      } else {
        while (__hip_atomic_load(bar + 16, __ATOMIC_ACQUIRE,
                                 __HIP_MEMORY_SCOPE_AGENT) <= gen)
          __builtin_amdgcn_s_sleep(2);
      }
      __hip_atomic_store(ggen, gen + 1, __ATOMIC_RELEASE,
                         __HIP_MEMORY_SCOPE_AGENT);
    } else {
      while (__hip_atomic_load(ggen, __ATOMIC_ACQUIRE,
                               __HIP_MEMORY_SCOPE_AGENT) <= gen)
        __builtin_amdgcn_s_sleep(2);
    }
  }
  __syncthreads();
  __threadfence();
}

// One GEMM phase. Block tile: 64 rows x 64 h-cols x 4 gates. 8 waves:
// wave w -> gate-pair gp=w&1 (gp0: i,f; gp1: g,o), h-col group h4=w>>1.
// x-role: K=1024 x-GEMM seeded from gbuf[L] + in-lane/LDS LSTM epilogue,
// c state in registers (cr). h-role: recurrent partial -> gbuf[(L+1)%3].
template <int L>
__device__ __forceinline__ void do_phase(
    bool xe, bool he, int t, const unsigned short* __restrict__ Wih_b,
    const unsigned short* __restrict__ Whh_b, unsigned short* __restrict__ h_b,
    float* __restrict__ gbuf, float* __restrict__ macc,
    const float* __restrict__ W1, const float* __restrict__ W2,
    char (*lds)[32768], float* xch, int role, int tile, int m0, int hc0,
    int tid, int w, int lane, int quad, int l16, int gp, int h4, int colh,
    int athr, float bs0, float bs1, float (&cr)[16]) {
  const bool run = role ? he : xe;
  if (!run) return;

  constexpr int PR = (L + 2) % 3;  // x input layer
  constexpr int LH = (L + 1) % 3;  // h-partial target layer
  const unsigned short* A =
      role ? (h_b + (size_t)LH * 524288) : (h_b + (size_t)PR * 524288);
  const unsigned short* W =
      role ? (Whh_b + (size_t)LH * 4194304) : (Wih_b + (size_t)L * 4194304);
  float* gb = gbuf + (size_t)(role ? LH : L) * 2097152;

  const unsigned short* gA = A + athr;
  const unsigned short* brow0 =
      W + (size_t)((2 * gp + 0) * 1024 + colh) * 1024 + quad * 8;
  const unsigned short* brow1 = brow0 + (size_t)1024 * 1024;

  const int wvb = w * 1024;
  const int rx = l16 & 7;

  // stage chunk 0 (64 rows x 256 K, XOR-swizzled 16B chunks)
#pragma unroll
  for (int j = 0; j < 4; ++j)
    gload_lds16(gA + j * 64, &lds[0][j * 8192 + wvb]);

  short8 bfr[4][2];  // depth-4 B prefetch
#pragma unroll
  for (int d = 0; d < 4; ++d) {
    bfr[d][0] = *(const short8*)(brow0 + d * 32);
    bfr[d][1] = *(const short8*)(brow1 + d * 32);
  }

  f32x4 acc[4][2];
  if (role == 0) {
#pragma unroll
    for (int mb = 0; mb < 4; ++mb)
#pragma unroll
      for (int gf = 0; gf < 2; ++gf)
        acc[mb][gf] = *(const f32x4*)(
            gb + (((size_t)(tile * 8 + w) * 8 + gf * 4 + mb) * 256 + lane * 4));
  } else {
    f32x4 z = {0.f, 0.f, 0.f, 0.f};
#pragma unroll
    for (int mb = 0; mb < 4; ++mb)
#pragma unroll
      for (int gf = 0; gf < 2; ++gf) acc[mb][gf] = z;
  }
  __syncthreads();  // chunk 0 staged

#pragma unroll
  for (int kc = 0; kc < 4; ++kc) {
    if (kc < 3) {
#pragma unroll
      for (int j = 0; j < 4; ++j)
        gload_lds16(gA + (kc + 1) * 256 + j * 64,
                    &lds[(kc + 1) & 1][j * 8192 + wvb]);
    }
    const char* base = lds[kc & 1];
    short8 afr[2][4];
#pragma unroll
    for (int mb = 0; mb < 4; ++mb) {
      const int cc = quad;
      afr[0][mb] = *(const short8*)(base + (cc >> 3) * 8192 +
                                    (mb * 16 + l16) * 128 +
                                    (((cc & 7) ^ rx) << 4));
    }
#pragma unroll
    for (int ks = 0; ks < 8; ++ks) {
      const int kg = kc * 8 + ks;
      short8 a0 = afr[ks & 1][0], a1 = afr[ks & 1][1];
      short8 a2 = afr[ks & 1][2], a3 = afr[ks & 1][3];
      short8 b0 = bfr[kg & 3][0], b1 = bfr[kg & 3][1];
      if (ks < 7) {
#pragma unroll
        for (int mb = 0; mb < 4; ++mb) {
          const int cc = (ks + 1) * 4 + quad;
          afr[(ks + 1) & 1][mb] =
              *(const short8*)(base + (cc >> 3) * 8192 + (mb * 16 + l16) * 128 +
                               (((cc & 7) ^ rx) << 4));
        }
      }
      if (kg + 4 < 32) {
        bfr[kg & 3][0] = *(const short8*)(brow0 + (kg + 4) * 32);
        bfr[kg & 3][1] = *(const short8*)(brow1 + (kg + 4) * 32);
      }
      acc[0][0] = mfma16(a0, b0, acc[0][0]);
      acc[1][0] = mfma16(a1, b0, acc[1][0]);
      acc[2][0] = mfma16(a2, b0, acc[2][0]);
      acc[3][0] = mfma16(a3, b0, acc[3][0]);
      acc[0][1] = mfma16(a0, b1, acc[0][1]);
      acc[1][1] = mfma16(a1, b1, acc[1][1]);
      acc[2][1] = mfma16(a2, b1, acc[2][1]);
      acc[3][1] = mfma16(a3, b1, acc[3][1]);
    }
    if (kc < 3) __syncthreads();
  }

  if (role == 1) {
#pragma unroll
    for (int mb = 0; mb < 4; ++mb)
#pragma unroll
      for (int gf = 0; gf < 2; ++gf)
        *(f32x4*)(gb + (((size_t)(tile * 8 + w) * 8 + gf * 4 + mb) * 256 +
                        lane * 4)) = acc[mb][gf];
    return;
  }

  // ---- x epilogue: gp0 exports i,f pre-acts via LDS; gp1 owns g,o + c,h ----
  const int c = h4 * 16 + l16;
  if (gp == 0) {
#pragma unroll
    for (int mb = 0; mb < 4; ++mb)
#pragma unroll
      for (int rr = 0; rr < 4; ++rr) {
        const int m = mb * 16 + quad * 4 + rr;
        xch[(0 * 64 + m) * 66 + c] = acc[mb][0][rr] + bs0;
        xch[(1 * 64 + m) * 66 + c] = acc[mb][1][rr] + bs1;
      }
  }
  __syncthreads();
  float hv[16];
  if (gp == 1) {
#pragma unroll
    for (int mb = 0; mb < 4; ++mb)
#pragma unroll
      for (int rr = 0; rr < 4; ++rr) {
        const int m = mb * 16 + quad * 4 + rr;
        const float giv = xch[(0 * 64 + m) * 66 + c];
        const float gfv = xch[(1 * 64 + m) * 66 + c];
        const float ggv = acc[mb][0][rr] + bs0;
        const float gov = acc[mb][1][rr] + bs1;
        const float cn = sigm(gfv) * cr[mb * 4 + rr] + sigm(giv) * tanh_f(ggv);
        cr[mb * 4 + rr] = cn;
        const float h = sigm(gov) * tanh_f(cn);
        hv[mb * 4 + rr] = h;
        h_b[(size_t)L * 524288 + (size_t)(m0 + m) * 1024 + colh] = f2bf(h);
      }
  }

  if (L == 2) {  // fused projection
    __syncthreads();  // i,f reads done; reuse xch as hbuf[64][66]
    if (gp == 1) {
#pragma unroll
      for (int mb = 0; mb < 4; ++mb)
#pragma unroll
        for (int rr = 0; rr < 4; ++rr)
          xch[(mb * 16 + quad * 4 + rr) * 66 + c] = hv[mb * 4 + rr];
    }
    __syncthreads();
    float* projred = (float*)lds[1];
    if (tid < 256) {
      const int grp = tid >> 6, m = tid & 63;
      float hj[16];
#pragma unroll
      for (int j = 0; j < 16; ++j) hj[j] = xch[m * 66 + grp * 16 + j];
#pragma unroll
      for (int tt = 0; tt < 8; ++tt) {
        const f32x4* w1p = (const f32x4*)(W1 + tt * 1024 + hc0 + grp * 16);
        const f32x4* w2p = (const f32x4*)(W2 + tt * 1024 + hc0 + grp * 16);
        float s1 = 0.f, s2 = 0.f;
#pragma unroll
        for (int v = 0; v < 4; ++v) {
          f32x4 wa = w1p[v], wb = w2p[v];
#pragma unroll
          for (int j = 0; j < 4; ++j) {
            s1 += hj[v * 4 + j] * wa[j];
            s2 += hj[v * 4 + j] * wb[j];
          }
        }
        projred[(grp * 64 + m) * 17 + tt] = s1;
        projred[(grp * 64 + m) * 17 + 8 + tt] = s2;
      }
    }
    __syncthreads();
    if (tid < 256) {
      const int grp = tid >> 6, m = tid & 63;
#pragma unroll
      for (int q = 0; q < 4; ++q) {
        const int s = grp * 4 + q;
        const float v = projred[m * 17 + s] + projred[(64 + m) * 17 + s] +
                        projred[(128 + m) * 17 + s] +
                        projred[(192 + m) * 17 + s];
        atomicAdd(&macc[((size_t)(m0 + m) * 96 + t) * 16 + s], v);
      }
    }
  }
}

__global__ __launch_bounds__(512, 2) void persist_kernel(
    const unsigned short* __restrict__ Wih_b,
    const unsigned short* __restrict__ Whh_b,
    unsigned short* __restrict__ h_b, const float* __restrict__ cell_in,
    const float* __restrict__ bias_g, float* __restrict__ gbuf,
    float* __restrict__ macc, const float* __restrict__ W1,
    const float* __restrict__ W2, int* bar) {
  __shared__ __align__(16) char lds[2][32768];
  __shared__ __align__(16) float xch[2 * 64 * 66];

  const int bi = blockIdx.x;
  // XCD-pinned decode: all 8 m-tiles of a (role,hcg) pair on one XCD.
  const int xcd = bi & 7, rslot = bi >> 3;
  const int pair = xcd * 4 + (rslot >> 3);
  const int mt = rslot & 7;
  const int role = pair & 1;
  const int hcg = pair >> 1;  // 0..15
  const int tile = hcg * 8 + mt;
  const int m0 = mt * 64, hc0 = hcg * 64;

  const int tid = threadIdx.x;
  const int w = tid >> 6, lane = tid & 63, quad = lane >> 4, l16 = lane & 15;
  const int gp = w & 1, h4 = w >> 1;
  const int colh = hc0 + h4 * 16 + l16;
  const int athr =
      (m0 + (tid >> 3)) * 1024 + (((tid & 7) ^ ((tid >> 3) & 7)) * 8);

  float bs[3][2];
#pragma unroll
  for (int l = 0; l < 3; ++l) {
    bs[l][0] = bias_g[l * 4096 + (2 * gp + 0) * 1024 + colh];
    bs[l][1] = bias_g[l * 4096 + (2 * gp + 1) * 1024 + colh];
  }

  // cell state lives in registers for the whole decode (x-role gp1 waves)
  float c0[16], c1[16], c2[16];
  if (role == 0 && gp == 1) {
#pragma unroll
    for (int mb = 0; mb < 4; ++mb)
#pragma unroll
      for (int rr = 0; rr < 4; ++rr) {
        const int m = m0 + mb * 16 + quad * 4 + rr;
        c0[mb * 4 + rr] = cell_in[(size_t)(0 * 512 + m) * 1024 + colh];
        c1[mb * 4 + rr] = cell_in[(size_t)(1 * 512 + m) * 1024 + colh];
        c2[mb * 4 + rr] = cell_in[(size_t)(2 * 512 + m) * 1024 + colh];
      }
  }

  int gen = 0;
  // bootstrap: h-role computes gbuf[0] from initial h0
  do_phase<2>(false, true, 0, Wih_b, Whh_b, h_b, gbuf, macc, W1, W2, lds, xch,
              role, tile, m0, hc0, tid, w, lane, quad, l16, gp, h4, colh, athr,
              bs[2][0], bs[2][1], c2);
  grid_barrier(bar, gen);
  ++gen;

#pragma unroll 1
  for (int t = 0; t < 96; ++t) {
    do_phase<0>(true, true, t, Wih_b, Whh_b, h_b, gbuf, macc, W1, W2, lds, xch,
                role, tile, m0, hc0, tid, w, lane, quad, l16, gp, h4, colh,
                athr, bs[0][0], bs[0][1], c0);
    grid_barrier(bar, gen);
    ++gen;
    do_phase<1>(true, true, t, Wih_b, Whh_b, h_b, gbuf, macc, W1, W2, lds, xch,
                role, tile, m0, hc0, tid, w, lane, quad, l16, gp, h4, colh,
                athr, bs[1][0], bs[1][1], c1);
    grid_barrier(bar, gen);
    ++gen;
    do_phase<2>(true, t < 95, t, Wih_b, Whh_b, h_b, gbuf, macc, W1, W2, lds,
                xch, role, tile, m0, hc0, tid, w, lane, quad, l16, gp, h4, colh,
                athr, bs[2][0], bs[2][1], c2);
    grid_barrier(bar, gen);
    ++gen;
  }
}

// ---------------------------------------------------------------------------
__global__ void conv_w(const f32x4* __restrict__ wi, const f32x4* __restrict__ wh,
                       u16x4* __restrict__ wib, u16x4* __restrict__ whb) {
  int i = blockIdx.x * 256 + threadIdx.x;  // 3145728 vec4
  f32x4 a = wi[i], b = wh[i];
  u16x4 pa, pb;
#pragma unroll
  for (int j = 0; j < 4; ++j) {
    pa[j] = f2bf(a[j]);
    pb[j] = f2bf(b[j]);
  }
  wib[i] = pa;
  whb[i] = pb;
}

__global__ void init_state(const f32x4* __restrict__ hid,
                           const f32x4* __restrict__ bih,
                           const f32x4* __restrict__ bhh,
                           u16x4* __restrict__ hb, f32x4* __restrict__ bias) {
  int i = blockIdx.x * 256 + threadIdx.x;  // 393216 vec4
  f32x4 h = hid[i];
  u16x4 p;
#pragma unroll
  for (int j = 0; j < 4; ++j) p[j] = f2bf(h[j]);
  hb[i] = p;
  if (i < 3072) bias[i] = bih[i] + bhh[i];
}

__global__ void finalize_k(const float* __restrict__ macc,
                           const float* __restrict__ b1,
                           const float* __restrict__ b2,
                           float* __restrict__ out) {
  int idx = blockIdx.x * 256 + threadIdx.x;  // 393216 = 512*96*8
  int t = idx & 7;
  int bt = idx >> 3;  // b*96+tau
  float mu = macc[bt * 16 + t] + b1[t];
  float z2 = 2.0f * (macc[bt * 16 + 8 + t] + b2[t]);
  float sp = fmaxf(z2, 0.f) + log1pf(__expf(-fabsf(z2)));
  out[idx] = mu;
  out[393216 + idx] = 0.5f * sp;
}

// ---------------------------------------------------------------------------
extern "C" void kernel_launch(void* const* d_in, const int* in_sizes, int n_in,
                              void* d_out, int out_size, void* d_ws,
                              size_t ws_size, hipStream_t stream) {
  (void)in_sizes; (void)n_in; (void)out_size; (void)ws_size;
  const float* hidden = (const float*)d_in[0];
  const float* cell = (const float*)d_in[1];
  const float* Wih = (const float*)d_in[2];
  const float* Whh = (const float*)d_in[3];
  const float* bih = (const float*)d_in[4];
  const float* bhh = (const float*)d_in[5];
  const float* W1 = (const float*)d_in[6];
  const float* b1 = (const float*)d_in[7];
  const float* W2 = (const float*)d_in[8];
  const float* b2 = (const float*)d_in[9];
  float* out = (float*)d_out;

  char* ws = (char*)d_ws;
  unsigned short* Wih_b = (unsigned short*)(ws);
  unsigned short* Whh_b = (unsigned short*)(ws + 25165824);
  unsigned short* h_b = (unsigned short*)(ws + 50331648);
  float* gbuf = (float*)(ws + 53477376);
  float* bias = (float*)(ws + 78643200);
  float* macc = (float*)(ws + 78692352);
  int* bar = (int*)(ws + 81838080);

  hipMemsetAsync(macc, 0, 3145728 + 4096, stream);  // macc + bar
  conv_w<<<12288, 256, 0, stream>>>((const f32x4*)Wih, (const f32x4*)Whh,
                                    (u16x4*)Wih_b, (u16x4*)Whh_b);
  init_state<<<1536, 256, 0, stream>>>((const f32x4*)hidden, (const f32x4*)bih,
                                       (const f32x4*)bhh, (u16x4*)h_b,
                                       (f32x4*)bias);
  persist_kernel<<<256, 512, 0, stream>>>(Wih_b, Whh_b, h_b, cell, bias, gbuf,
                                          macc, W1, W2, bar);
  finalize_k<<<1536, 256, 0, stream>>>(macc, b1, b2, out);
}

// Round 5
// 21751.068 us; speedup vs baseline: 2.8692x; 2.8692x over previous
//
#include <hip/hip_runtime.h>
#include <hip/hip_bf16.h>
#include <stdint.h>

// DeepAR decoder: L=3, B=512, H=1024, TAU=96, T=8, BETA=2
// Persistent-kernel version: all 289 GEMM phases in ONE kernel with a
// device-scope grid barrier between phases. grid=256 blocks x 512 thr,
// 99 KB LDS/block -> exactly 1 block/CU (co-residency guaranteed).
//
// Round-5 change: grid barrier rewritten. Round-4 polled with ACQUIRE-scope
// atomic loads (each emits an XCD-wide L2 invalidate on gfx950) and ran
// __threadfence in all 512 threads -> invalidate storm, 208us/phase at 1.6%
// MfmaUtil. Now: leader-only release fence, RELAXED arrive + RELAXED polls,
// leader-only acquire fence after the generation flips.
//
// ws layout (bytes):
//   Wih_b  bf16 [3][4096][1024]   @ 0          (25165824)
//   Whh_b  bf16 [3][4096][1024]   @ 25165824   (25165824)
//   h_b    bf16 [3][512][1024]    @ 50331648   (3145728)
//   gbuf   f32  [3][2M]           @ 53477376   (25165824)  (MFMA C-layout tiles)
//   bias   f32  [3][4096]         @ 78643200   (49152)
//   macc   f32  [512][96][16]     @ 78692352   (3145728)
//   bar    int  [1024]            @ 81838080   (4096)

typedef __attribute__((ext_vector_type(8))) short short8;
typedef __attribute__((ext_vector_type(8))) __bf16 bf16x8_t;
typedef __attribute__((ext_vector_type(4))) float f32x4;
typedef __attribute__((ext_vector_type(4))) unsigned short u16x4;

static __device__ __forceinline__ unsigned short f2bf(float f) {
  unsigned int u = __float_as_uint(f);
  u += 0x7FFFu + ((u >> 16) & 1u);  // RNE
  return (unsigned short)(u >> 16);
}
static __device__ __forceinline__ float sigm(float x) {
  return 1.0f / (1.0f + __expf(-x));
}
static __device__ __forceinline__ float tanh_f(float x) {
  float xc = fminf(fmaxf(x, -15.f), 15.f);
  float e = __expf(2.0f * xc);
  return 1.0f - 2.0f / (e + 1.0f);
}
static __device__ __forceinline__ void gload_lds16(const void* g, void* l) {
  __builtin_amdgcn_global_load_lds(
      (const __attribute__((address_space(1))) unsigned int*)g,
      (__attribute__((address_space(3))) unsigned int*)l, 16, 0, 0);
}
static __device__ __forceinline__ f32x4 mfma16(short8 a, short8 b, f32x4 c) {
  return __builtin_amdgcn_mfma_f32_16x16x32_bf16((bf16x8_t)a, (bf16x8_t)b, c, 0, 0, 0);
}

// Two-level grid barrier, 8 groups x 32 blocks.
// Leader-only fences; RELAXED polls (agent-scope loads bypass L2 without
// invalidating it). Counter layout: bar[0]=root count, bar[16]=root gen,
// group g: count at bar[32+g*64], gen at bar[32+g*64+32] (separate lines).
static __device__ __forceinline__ void grid_barrier(int* bar, int gen) {
  __syncthreads();  // all waves' prior stores issued (vmcnt drained at barrier)
  if (threadIdx.x == 0) {
    __threadfence();  // release: write-back this XCD's dirty L2 once
    const int g = blockIdx.x >> 5;
    int* gcnt = bar + 32 + g * 64;
    int* ggen = gcnt + 32;
    if (__hip_atomic_fetch_add(gcnt, 1, __ATOMIC_RELAXED,
                               __HIP_MEMORY_SCOPE_AGENT) == 31) {
      if (__hip_atomic_fetch_add(bar, 1, __ATOMIC_RELAXED,
                                 __HIP_MEMORY_SCOPE_AGENT) == 7) {
        __hip_atomic_store(bar, 0, __ATOMIC_RELAXED, __HIP_MEMORY_SCOPE_AGENT);
        __hip_atomic_store(bar + 16, gen + 1, __ATOMIC_RELAXED,
                           __HIP_MEMORY_SCOPE_AGENT);
      } else {
        while (__hip_atomic_load(bar + 16, __ATOMIC_RELAXED,
                                 __HIP_MEMORY_SCOPE_AGENT) <= gen)
          __builtin_amdgcn_s_sleep(4);
      }
      __hip_atomic_store(gcnt, 0, __ATOMIC_RELAXED, __HIP_MEMORY_SCOPE_AGENT);
      __hip_atomic_store(ggen, gen + 1, __ATOMIC_RELAXED,
                         __HIP_MEMORY_SCOPE_AGENT);
    } else {
      while (__hip_atomic_load(ggen, __ATOMIC_RELAXED,
                               __HIP_MEMORY_SCOPE_AGENT) <= gen)
        __builtin_amdgcn_s_sleep(4);
    }
    __threadfence();  // acquire: invalidate this CU's L1 + XCD L2 once
  }
  __syncthreads();
}

// One GEMM phase. Block tile: 64 rows x 64 h-cols x 4 gates. 8 waves:
// wave w -> gate-pair gp=w&1 (gp0: i,f; gp1: g,o), h-col group h4=w>>1.
// x-role: K=1024 x-GEMM seeded from gbuf[L] + in-lane/LDS LSTM epilogue,
// c state in registers (cr). h-role: recurrent partial -> gbuf[(L+1)%3].
template <int L>
__device__ __forceinline__ void do_phase(
    bool xe, bool he, int t, const unsigned short* __restrict__ Wih_b,
    const unsigned short* __restrict__ Whh_b, unsigned short* __restrict__ h_b,
    float* __restrict__ gbuf, float* __restrict__ macc,
    const float* __restrict__ W1, const float* __restrict__ W2,
    char (*lds)[32768], float* xch, int role, int tile, int m0, int hc0,
    int tid, int w, int lane, int quad, int l16, int gp, int h4, int colh,
    int athr, float bs0, float bs1, float (&cr)[16]) {
  const bool run = role ? he : xe;
  if (!run) return;

  constexpr int PR = (L + 2) % 3;  // x input layer
  constexpr int LH = (L + 1) % 3;  // h-partial target layer
  const unsigned short* A =
      role ? (h_b + (size_t)LH * 524288) : (h_b + (size_t)PR * 524288);
  const unsigned short* W =
      role ? (Whh_b + (size_t)LH * 4194304) : (Wih_b + (size_t)L * 4194304);
  float* gb = gbuf + (size_t)(role ? LH : L) * 2097152;

  const unsigned short* gA = A + athr;
  const unsigned short* brow0 =
      W + (size_t)((2 * gp + 0) * 1024 + colh) * 1024 + quad * 8;
  const unsigned short* brow1 = brow0 + (size_t)1024 * 1024;

  const int wvb = w * 1024;
  const int rx = l16 & 7;

  // stage chunk 0 (64 rows x 256 K, XOR-swizzled 16B chunks)
#pragma unroll
  for (int j = 0; j < 4; ++j)
    gload_lds16(gA + j * 64, &lds[0][j * 8192 + wvb]);

  short8 bfr[4][2];  // depth-4 B prefetch
#pragma unroll
  for (int d = 0; d < 4; ++d) {
    bfr[d][0] = *(const short8*)(brow0 + d * 32);
    bfr[d][1] = *(const short8*)(brow1 + d * 32);
  }

  f32x4 acc[4][2];
  if (role == 0) {
#pragma unroll
    for (int mb = 0; mb < 4; ++mb)
#pragma unroll
      for (int gf = 0; gf < 2; ++gf)
        acc[mb][gf] = *(const f32x4*)(
            gb + (((size_t)(tile * 8 + w) * 8 + gf * 4 + mb) * 256 + lane * 4));
  } else {
    f32x4 z = {0.f, 0.f, 0.f, 0.f};
#pragma unroll
    for (int mb = 0; mb < 4; ++mb)
#pragma unroll
      for (int gf = 0; gf < 2; ++gf) acc[mb][gf] = z;
  }
  __syncthreads();  // chunk 0 staged

#pragma unroll
  for (int kc = 0; kc < 4; ++kc) {
    if (kc < 3) {
#pragma unroll
      for (int j = 0; j < 4; ++j)
        gload_lds16(gA + (kc + 1) * 256 + j * 64,
                    &lds[(kc + 1) & 1][j * 8192 + wvb]);
    }
    const char* base = lds[kc & 1];
    short8 afr[2][4];
#pragma unroll
    for (int mb = 0; mb < 4; ++mb) {
      const int cc = quad;
      afr[0][mb] = *(const short8*)(base + (cc >> 3) * 8192 +
                                    (mb * 16 + l16) * 128 +
                                    (((cc & 7) ^ rx) << 4));
    }
#pragma unroll
    for (int ks = 0; ks < 8; ++ks) {
      const int kg = kc * 8 + ks;
      short8 a0 = afr[ks & 1][0], a1 = afr[ks & 1][1];
      short8 a2 = afr[ks & 1][2], a3 = afr[ks & 1][3];
      short8 b0 = bfr[kg & 3][0], b1 = bfr[kg & 3][1];
      if (ks < 7) {
#pragma unroll
        for (int mb = 0; mb < 4; ++mb) {
          const int cc = (ks + 1) * 4 + quad;
          afr[(ks + 1) & 1][mb] =
              *(const short8*)(base + (cc >> 3) * 8192 + (mb * 16 + l16) * 128 +
                               (((cc & 7) ^ rx) << 4));
        }
      }
      if (kg + 4 < 32) {
        bfr[kg & 3][0] = *(const short8*)(brow0 + (kg + 4) * 32);
        bfr[kg & 3][1] = *(const short8*)(brow1 + (kg + 4) * 32);
      }
      acc[0][0] = mfma16(a0, b0, acc[0][0]);
      acc[1][0] = mfma16(a1, b0, acc[1][0]);
      acc[2][0] = mfma16(a2, b0, acc[2][0]);
      acc[3][0] = mfma16(a3, b0, acc[3][0]);
      acc[0][1] = mfma16(a0, b1, acc[0][1]);
      acc[1][1] = mfma16(a1, b1, acc[1][1]);
      acc[2][1] = mfma16(a2, b1, acc[2][1]);
      acc[3][1] = mfma16(a3, b1, acc[3][1]);
    }
    if (kc < 3) __syncthreads();
  }

  if (role == 1) {
#pragma unroll
    for (int mb = 0; mb < 4; ++mb)
#pragma unroll
      for (int gf = 0; gf < 2; ++gf)
        *(f32x4*)(gb + (((size_t)(tile * 8 + w) * 8 + gf * 4 + mb) * 256 +
                        lane * 4)) = acc[mb][gf];
    return;
  }

  // ---- x epilogue: gp0 exports i,f pre-acts via LDS; gp1 owns g,o + c,h ----
  const int c = h4 * 16 + l16;
  if (gp == 0) {
#pragma unroll
    for (int mb = 0; mb < 4; ++mb)
#pragma unroll
      for (int rr = 0; rr < 4; ++rr) {
        const int m = mb * 16 + quad * 4 + rr;
        xch[(0 * 64 + m) * 66 + c] = acc[mb][0][rr] + bs0;
        xch[(1 * 64 + m) * 66 + c] = acc[mb][1][rr] + bs1;
      }
  }
  __syncthreads();
  float hv[16];
  if (gp == 1) {
#pragma unroll
    for (int mb = 0; mb < 4; ++mb)
#pragma unroll
      for (int rr = 0; rr < 4; ++rr) {
        const int m = mb * 16 + quad * 4 + rr;
        const float giv = xch[(0 * 64 + m) * 66 + c];
        const float gfv = xch[(1 * 64 + m) * 66 + c];
        const float ggv = acc[mb][0][rr] + bs0;
        const float gov = acc[mb][1][rr] + bs1;
        const float cn = sigm(gfv) * cr[mb * 4 + rr] + sigm(giv) * tanh_f(ggv);
        cr[mb * 4 + rr] = cn;
        const float h = sigm(gov) * tanh_f(cn);
        hv[mb * 4 + rr] = h;
        h_b[(size_t)L * 524288 + (size_t)(m0 + m) * 1024 + colh] = f2bf(h);
      }
  }

  if (L == 2) {  // fused projection
    __syncthreads();  // i,f reads done; reuse xch as hbuf[64][66]
    if (gp == 1) {
#pragma unroll
      for (int mb = 0; mb < 4; ++mb)
#pragma unroll
        for (int rr = 0; rr < 4; ++rr)
          xch[(mb * 16 + quad * 4 + rr) * 66 + c] = hv[mb * 4 + rr];
    }
    __syncthreads();
    float* projred = (float*)lds[1];
    if (tid < 256) {
      const int grp = tid >> 6, m = tid & 63;
      float hj[16];
#pragma unroll
      for (int j = 0; j < 16; ++j) hj[j] = xch[m * 66 + grp * 16 + j];
#pragma unroll
      for (int tt = 0; tt < 8; ++tt) {
        const f32x4* w1p = (const f32x4*)(W1 + tt * 1024 + hc0 + grp * 16);
        const f32x4* w2p = (const f32x4*)(W2 + tt * 1024 + hc0 + grp * 16);
        float s1 = 0.f, s2 = 0.f;
#pragma unroll
        for (int v = 0; v < 4; ++v) {
          f32x4 wa = w1p[v], wb = w2p[v];
#pragma unroll
          for (int j = 0; j < 4; ++j) {
            s1 += hj[v * 4 + j] * wa[j];
            s2 += hj[v * 4 + j] * wb[j];
          }
        }
        projred[(grp * 64 + m) * 17 + tt] = s1;
        projred[(grp * 64 + m) * 17 + 8 + tt] = s2;
      }
    }
    __syncthreads();
    if (tid < 256) {
      const int grp = tid >> 6, m = tid & 63;
#pragma unroll
      for (int q = 0; q < 4; ++q) {
        const int s = grp * 4 + q;
        const float v = projred[m * 17 + s] + projred[(64 + m) * 17 + s] +
                        projred[(128 + m) * 17 + s] +
                        projred[(192 + m) * 17 + s];
        atomicAdd(&macc[((size_t)(m0 + m) * 96 + t) * 16 + s], v);
      }
    }
  }
}

__global__ __launch_bounds__(512, 2) void persist_kernel(
    const unsigned short* __restrict__ Wih_b,
    const unsigned short* __restrict__ Whh_b,
    unsigned short* __restrict__ h_b, const float* __restrict__ cell_in,
    const float* __restrict__ bias_g, float* __restrict__ gbuf,
    float* __restrict__ macc, const float* __restrict__ W1,
    const float* __restrict__ W2, int* bar) {
  __shared__ __align__(16) char lds[2][32768];
  __shared__ __align__(16) float xch[2 * 64 * 66];

  const int bi = blockIdx.x;
  // XCD-pinned decode: all 8 m-tiles of a (role,hcg) pair on one XCD.
  const int xcd = bi & 7, rslot = bi >> 3;
  const int pair = xcd * 4 + (rslot >> 3);
  const int mt = rslot & 7;
  const int role = pair & 1;
  const int hcg = pair >> 1;  // 0..15
  const int tile = hcg * 8 + mt;
  const int m0 = mt * 64, hc0 = hcg * 64;

  const int tid = threadIdx.x;
  const int w = tid >> 6, lane = tid & 63, quad = lane >> 4, l16 = lane & 15;
  const int gp = w & 1, h4 = w >> 1;
  const int colh = hc0 + h4 * 16 + l16;
  const int athr =
      (m0 + (tid >> 3)) * 1024 + (((tid & 7) ^ ((tid >> 3) & 7)) * 8);

  float bs[3][2];
#pragma unroll
  for (int l = 0; l < 3; ++l) {
    bs[l][0] = bias_g[l * 4096 + (2 * gp + 0) * 1024 + colh];
    bs[l][1] = bias_g[l * 4096 + (2 * gp + 1) * 1024 + colh];
  }

  // cell state lives in registers for the whole decode (x-role gp1 waves)
  float c0[16], c1[16], c2[16];
  if (role == 0 && gp == 1) {
#pragma unroll
    for (int mb = 0; mb < 4; ++mb)
#pragma unroll
      for (int rr = 0; rr < 4; ++rr) {
        const int m = m0 + mb * 16 + quad * 4 + rr;
        c0[mb * 4 + rr] = cell_in[(size_t)(0 * 512 + m) * 1024 + colh];
        c1[mb * 4 + rr] = cell_in[(size_t)(1 * 512 + m) * 1024 + colh];
        c2[mb * 4 + rr] = cell_in[(size_t)(2 * 512 + m) * 1024 + colh];
      }
  }

  int gen = 0;
  // bootstrap: h-role computes gbuf[0] from initial h0
  do_phase<2>(false, true, 0, Wih_b, Whh_b, h_b, gbuf, macc, W1, W2, lds, xch,
              role, tile, m0, hc0, tid, w, lane, quad, l16, gp, h4, colh, athr,
              bs[2][0], bs[2][1], c2);
  grid_barrier(bar, gen);
  ++gen;

#pragma unroll 1
  for (int t = 0; t < 96; ++t) {
    do_phase<0>(true, true, t, Wih_b, Whh_b, h_b, gbuf, macc, W1, W2, lds, xch,
                role, tile, m0, hc0, tid, w, lane, quad, l16, gp, h4, colh,
                athr, bs[0][0], bs[0][1], c0);
    grid_barrier(bar, gen);
    ++gen;
    do_phase<1>(true, true, t, Wih_b, Whh_b, h_b, gbuf, macc, W1, W2, lds, xch,
                role, tile, m0, hc0, tid, w, lane, quad, l16, gp, h4, colh,
                athr, bs[1][0], bs[1][1], c1);
    grid_barrier(bar, gen);
    ++gen;
    do_phase<2>(true, t < 95, t, Wih_b, Whh_b, h_b, gbuf, macc, W1, W2, lds,
                xch, role, tile, m0, hc0, tid, w, lane, quad, l16, gp, h4, colh,
                athr, bs[2][0], bs[2][1], c2);
    grid_barrier(bar, gen);
    ++gen;
  }
}

// ---------------------------------------------------------------------------
__global__ void conv_w(const f32x4* __restrict__ wi, const f32x4* __restrict__ wh,
                       u16x4* __restrict__ wib, u16x4* __restrict__ whb) {
  int i = blockIdx.x * 256 + threadIdx.x;  // 3145728 vec4
  f32x4 a = wi[i], b = wh[i];
  u16x4 pa, pb;
#pragma unroll
  for (int j = 0; j < 4; ++j) {
    pa[j] = f2bf(a[j]);
    pb[j] = f2bf(b[j]);
  }
  wib[i] = pa;
  whb[i] = pb;
}

__global__ void init_state(const f32x4* __restrict__ hid,
                           const f32x4* __restrict__ bih,
                           const f32x4* __restrict__ bhh,
                           u16x4* __restrict__ hb, f32x4* __restrict__ bias) {
  int i = blockIdx.x * 256 + threadIdx.x;  // 393216 vec4
  f32x4 h = hid[i];
  u16x4 p;
#pragma unroll
  for (int j = 0; j < 4; ++j) p[j] = f2bf(h[j]);
  hb[i] = p;
  if (i < 3072) bias[i] = bih[i] + bhh[i];
}

__global__ void finalize_k(const float* __restrict__ macc,
                           const float* __restrict__ b1,
                           const float* __restrict__ b2,
                           float* __restrict__ out) {
  int idx = blockIdx.x * 256 + threadIdx.x;  // 393216 = 512*96*8
  int t = idx & 7;
  int bt = idx >> 3;  // b*96+tau
  float mu = macc[bt * 16 + t] + b1[t];
  float z2 = 2.0f * (macc[bt * 16 + 8 + t] + b2[t]);
  float sp = fmaxf(z2, 0.f) + log1pf(__expf(-fabsf(z2)));
  out[idx] = mu;
  out[393216 + idx] = 0.5f * sp;
}

// ---------------------------------------------------------------------------
extern "C" void kernel_launch(void* const* d_in, const int* in_sizes, int n_in,
                              void* d_out, int out_size, void* d_ws,
                              size_t ws_size, hipStream_t stream) {
  (void)in_sizes; (void)n_in; (void)out_size; (void)ws_size;
  const float* hidden = (const float*)d_in[0];
  const float* cell = (const float*)d_in[1];
  const float* Wih = (const float*)d_in[2];
  const float* Whh = (const float*)d_in[3];
  const float* bih = (const float*)d_in[4];
  const float* bhh = (const float*)d_in[5];
  const float* W1 = (const float*)d_in[6];
  const float* b1 = (const float*)d_in[7];
  const float* W2 = (const float*)d_in[8];
  const float* b2 = (const float*)d_in[9];
  float* out = (float*)d_out;

  char* ws = (char*)d_ws;
  unsigned short* Wih_b = (unsigned short*)(ws);
  unsigned short* Whh_b = (unsigned short*)(ws + 25165824);
  unsigned short* h_b = (unsigned short*)(ws + 50331648);
  float* gbuf = (float*)(ws + 53477376);
  float* bias = (float*)(ws + 78643200);
  float* macc = (float*)(ws + 78692352);
  int* bar = (int*)(ws + 81838080);

  hipMemsetAsync(macc, 0, 3145728 + 4096, stream);  // macc + bar
  conv_w<<<12288, 256, 0, stream>>>((const f32x4*)Wih, (const f32x4*)Whh,
                                    (u16x4*)Wih_b, (u16x4*)Whh_b);
  init_state<<<1536, 256, 0, stream>>>((const f32x4*)hidden, (const f32x4*)bih,
                                       (const f32x4*)bhh, (u16x4*)h_b,
                                       (f32x4*)bias);
  persist_kernel<<<256, 512, 0, stream>>>(Wih_b, Whh_b, h_b, cell, bias, gbuf,
                                          macc, W1, W2, bar);
  finalize_k<<<1536, 256, 0, stream>>>(macc, b1, b2, out);
}